// Round 7
// baseline (21184.560 us; speedup 1.0000x reference)
//
#include <hip/hip_runtime.h>
#include <hip/hip_bf16.h>

#define LSEQ  1024
#define DEPTH 4
#define NTILE 97

typedef __attribute__((ext_vector_type(8))) short short8;
typedef __attribute__((ext_vector_type(4))) float f32x4;

static __device__ __forceinline__ short f2bf(float f) {
    unsigned u = __builtin_bit_cast(unsigned, f);
    u += 0x7fffu + ((u >> 16) & 1u);
    return (short)(u >> 16);
}
static __device__ __forceinline__ float sigm(float x) { return __fdividef(1.f, 1.f + __expf(-x)); }
// tanh(g/2) = 2*sigmoid(g)-1
static __device__ __forceinline__ float tanh2(float g) { return 1.f - 2.f * __fdividef(1.f, 1.f + __expf(g)); }

static __device__ __forceinline__ void st32f(int* p, int v) { __hip_atomic_store(p, v, __ATOMIC_RELAXED, __HIP_MEMORY_SCOPE_AGENT); }
static __device__ __forceinline__ int  ld32f(const int* p) { return __hip_atomic_load(p, __ATOMIC_RELAXED, __HIP_MEMORY_SCOPE_AGENT); }
static __device__ __forceinline__ void st64g(unsigned long long* p, unsigned long long v) { __hip_atomic_store(p, v, __ATOMIC_RELAXED, __HIP_MEMORY_SCOPE_AGENT); }
static __device__ __forceinline__ unsigned long long ld64g(const unsigned long long* p) { return __hip_atomic_load(p, __ATOMIC_RELAXED, __HIP_MEMORY_SCOPE_AGENT); }

extern "C" __global__ void __launch_bounds__(512, 1)
ctlstm_kernel(const float* __restrict__ x, const float* __restrict__ td,
              const float* __restrict__ Wi, const float* __restrict__ bi,
              const float* __restrict__ Wf, const float* __restrict__ bf,
              const float* __restrict__ Wie, const float* __restrict__ bie,
              const float* __restrict__ Wfe, const float* __restrict__ bfe,
              const float* __restrict__ Wz, const float* __restrict__ bz,
              const float* __restrict__ Wo, const float* __restrict__ bo,
              const float* __restrict__ Wd, const float* __restrict__ bdp,
              const float* __restrict__ betap,
              float* __restrict__ out,
              int* __restrict__ pflags, int* __restrict__ cflags,
              float* __restrict__ ring, unsigned short* __restrict__ wsW,
              int ncopies)
{
    const int tid  = threadIdx.x;
    const int w    = tid >> 6;      // wave 0..7
    const int lane = tid & 63;
    const int l16  = lane & 15;
    const int lhi  = lane >> 4;

    if (blockIdx.x < 4) {
        // ============ CONSUMER: ONE block per batch-group g ============
        // wave w owns ALL 6 gates for columns [w*32, w*32+32): gates stay in-lane.
        // Weights: bf16, fragment-ordered, streamed from own L2 every step.
        const int g = blockIdx.x;

        __shared__ __align__(16) unsigned short h_lds[2 * 16 * 256]; // 16 KB dbuf
        __shared__ __align__(16) float dvals[16];

        unsigned short* wc = wsW + (size_t)(g % ncopies) * ((size_t)NTILE * 4096);

        // zero h LDS (2048 ull)
        #pragma unroll
        for (int i = 0; i < 4; ++i) ((unsigned long long*)h_lds)[tid + i * 512] = 0ull;

        const float beta = betap[0];

        // ---- one-time: convert W (h-part rows 256..511) to bf16 frag layout ----
        // thread (w, lane) handles kk = w for every tile ct.
        for (int ct = 0; ct < NTILE; ++ct) {
            short8 f;
            if (ct == 96) {
                #pragma unroll
                for (int e = 0; e < 8; ++e) {
                    const int k = w * 32 + lhi * 8 + e;
                    f[e] = (l16 == 0) ? f2bf(Wd[256 + k]) : (short)0;
                }
            } else {
                const int gt = ct >> 4, jt = ct & 15;
                const float* Wg;
                switch (gt) {
                    case 0: Wg = Wi;  break;
                    case 1: Wg = Wf;  break;
                    case 2: Wg = Wie; break;
                    case 3: Wg = Wfe; break;
                    case 4: Wg = Wz;  break;
                    default: Wg = Wo; break;
                }
                const int col = jt * 16 + l16;
                #pragma unroll
                for (int e = 0; e < 8; ++e) {
                    const int k = w * 32 + lhi * 8 + e;
                    f[e] = f2bf(Wg[(256 + k) * 256 + col]);
                }
            }
            *(short8*)&wc[((size_t)ct * 8 + w) * 64 * 8 + (size_t)lane * 8] = f;
        }

        // per-wave tile table: i 0..5 = gates i,f,ie,fe,z,o @ jt=2w;
        // 6..9 = i,f,ie,fe @ jt=2w+1; 10,11 = z,o @ jt=2w+1; 12 = delta (wave 0)
        int ctv[13];
        #pragma unroll
        for (int i = 0; i < 6; ++i)  ctv[i] = i * 16 + 2 * w;
        #pragma unroll
        for (int i = 6; i < 10; ++i) ctv[i] = (i - 6) * 16 + 2 * w + 1;
        ctv[10] = 64 + 2 * w + 1;
        ctv[11] = 80 + 2 * w + 1;
        ctv[12] = 96;
        int woff[13];
        #pragma unroll
        for (int i = 0; i < 13; ++i) woff[i] = ctv[i] * 4096 + lane * 8;

        const int rowb = lhi * 4;            // this lane's 4 batch rows
        const int colb = w * 32 + l16;       // this lane's base column
        float cC[8], ceS[8], hreg[8];
        #pragma unroll
        for (int i = 0; i < 8; ++i) { cC[i] = 0.f; ceS[i] = 0.f; hreg[i] = 0.f; }

        f32x4 acc[13];
        auto load_gx = [&](int slot) {
            #pragma unroll
            for (int i = 0; i < 13; ++i) {
                if (i < 12 || w == 0) {
                    const unsigned long long* pp = (const unsigned long long*)
                        &ring[((size_t)(slot * 4 + g) * NTILE + ctv[i]) * 256 + lane * 4];
                    union { unsigned long long q[2]; f32x4 v; } u;
                    u.q[0] = ld64g(pp); u.q[1] = ld64g(pp + 1);
                    acc[i] = u.v;
                }
            }
        };

        // prologue: producers finished steps 0,1
        {
            int v = (lane < 4) ? ld32f(&pflags[(lane * 4 + g) * 32]) : 0x7fffffff;
            while (__any(v < 2)) {
                __builtin_amdgcn_s_sleep(8);
                v = (lane < 4) ? ld32f(&pflags[(lane * 4 + g) * 32]) : 0x7fffffff;
            }
        }
        load_gx(0);
        __syncthreads();   // wc conversion + h zero visible

        for (int t = 0; t < LSEQ; ++t) {
            // td prefetch for t+1
            float tdv[4];
            if (t + 1 < LSEQ) {
                #pragma unroll
                for (int q = 0; q < 4; ++q)
                    tdv[q] = td[(size_t)(g * 16 + rowb + q) * LSEQ + (t + 1)];
            }
            // A fragments: h(t) from LDS (parity t&1), XOR-swizzled rows
            short8 hf[8];
            const int parh = (t & 1) * 8192;
            #pragma unroll
            for (int kk = 0; kk < 8; ++kk) {
                const int bo = parh + l16 * 512 + ((kk * 64 + lhi * 16) ^ ((l16 & 7) << 4));
                hf[kk] = *(const short8*)((const char*)h_lds + bo);
            }
            // stream weights from L2 + MFMA
            #pragma unroll
            for (int i = 0; i < 13; ++i) {
                if (i < 12 || w == 0) {
                    short8 wb[8];
                    #pragma unroll
                    for (int kk = 0; kk < 8; ++kk)
                        wb[kk] = *(const short8*)&wc[(size_t)woff[i] + kk * 512];
                    #pragma unroll
                    for (int kk = 0; kk < 8; ++kk)
                        acc[i] = __builtin_amdgcn_mfma_f32_16x16x32_bf16(hf[kk], wb[kk], acc[i], 0, 0, 0);
                }
            }
            // delta head -> dvals (wave 0, col 0 lanes)
            if (w == 0 && l16 == 0) {
                #pragma unroll
                for (int q = 0; q < 4; ++q) {
                    const float bg_ = beta * acc[12][q];
                    const float sp  = fmaxf(bg_, 0.f) + __logf(1.f + __expf(-fabsf(bg_)));
                    dvals[rowb + q] = __fdividef(sp, beta);
                }
            }
            // activations (in-lane; frees acc for prefetch)
            float gv[2][6][4];
            #pragma unroll
            for (int jtl = 0; jtl < 2; ++jtl) {
                #pragma unroll
                for (int gt2 = 0; gt2 < 6; ++gt2) {
                    const int ai = (jtl == 0) ? gt2
                                 : (gt2 < 4 ? 6 + gt2 : (gt2 == 4 ? 10 : 11));
                    #pragma unroll
                    for (int q = 0; q < 4; ++q) {
                        const float v = acc[ai][q];
                        gv[jtl][gt2][q] = (gt2 == 4) ? tanh2(v) : sigm(v);
                    }
                }
            }
            // prefetch Gx(t+1) into acc; early-issue pflags poll
            if (t + 1 < LSEQ) load_gx((t + 1) & (DEPTH - 1));
            int pv = 0x7fffffff;
            if (t + 1 < LSEQ && lane < 4) pv = ld32f(&pflags[(lane * 4 + g) * 32]);

            __syncthreads();   // bar1: dvals ready; all waves past gx[t]
            if (tid == 0) st32f(&cflags[g * 32], t + 1);

            // ---- state update (all in-lane) ----
            const f32x4 dvv = *(const f32x4*)&dvals[rowb];
            #pragma unroll
            for (int jtl = 0; jtl < 2; ++jtl)
                #pragma unroll
                for (int q = 0; q < 4; ++q)
                    out[((size_t)(g * 16 + rowb + q) * LSEQ + t) * 256 + colb + jtl * 16]
                        = hreg[jtl * 4 + q];

            float e4[4];
            if (t + 1 < LSEQ) {
                #pragma unroll
                for (int q = 0; q < 4; ++q) e4[q] = __expf(-dvv[q] * tdv[q]);
            }
            #pragma unroll
            for (int jtl = 0; jtl < 2; ++jtl) {
                #pragma unroll
                for (int q = 0; q < 4; ++q) {
                    const int idx = jtl * 4 + q;
                    const int row = rowb + q;
                    const int col = colb + jtl * 16;
                    const float iv  = gv[jtl][0][q], fv  = gv[jtl][1][q];
                    const float iev = gv[jtl][2][q], fev = gv[jtl][3][q];
                    const float zv  = gv[jtl][4][q], ov  = gv[jtl][5][q];
                    const float cs = fv * cC[idx] + iv * zv;
                    const float ce = fev * ceS[idx] + iev * zv;
                    if (t + 1 < LSEQ) {
                        const float cn = cs + (ce - cs) * e4[q];
                        const float hv = ov * tanh2(2.f * cn);
                        cC[idx] = cn; ceS[idx] = ce; hreg[idx] = hv;
                        *(unsigned short*)((char*)h_lds + (((t + 1) & 1) * 8192)
                            + row * 512 + ((col * 2) ^ ((row & 7) << 4)))
                            = (unsigned short)f2bf(hv);
                    } else {
                        float* so2 = out + (size_t)64 * LSEQ * 256 + (size_t)(g * 16 + row) * 769;
                        so2[col]       = ov;
                        so2[256 + col] = cs;
                        so2[512 + col] = ce;
                        if (w == 0 && l16 == 0 && jtl == 0) so2[768] = dvv[q];
                    }
                }
            }
            // late poll verify: entering t+1, pflags >= min(t+3, LSEQ)
            if (t + 1 < LSEQ) {
                const int tgt = (t + 3 <= LSEQ) ? (t + 3) : LSEQ;
                while (__any(pv < tgt)) {
                    __builtin_amdgcn_s_sleep(2);
                    pv = (lane < 4) ? ld32f(&pflags[(lane * 4 + g) * 32]) : 0x7fffffff;
                }
            }
            __syncthreads();   // bar3: h(t+1) in LDS
        }
    } else {
        // ===================== PRODUCER block p (R6-verbatim) =====================
        const int p  = blockIdx.x - 4;    // 0..15
        const int g  = p & 3;
        const int qt = p >> 2;
        const int base_ct = qt * 24 + w * 3;
        const int nt = (qt == 3 && w == 7) ? 4 : 3;

        short8 wx[4][8];
        f32x4 bias[4];
        #pragma unroll
        for (int i = 0; i < 4; ++i) {
            if (i < nt) {
                const int ct = base_ct + i;
                if (ct == 96) {
                    const float bv = (l16 == 0) ? bdp[0] : 0.f;
                    bias[i] = f32x4{bv, bv, bv, bv};
                    #pragma unroll
                    for (int kk = 0; kk < 8; ++kk) {
                        short8 f;
                        #pragma unroll
                        for (int e = 0; e < 8; ++e)
                            f[e] = (l16 == 0) ? f2bf(Wd[kk * 32 + lhi * 8 + e]) : (short)0;
                        wx[i][kk] = f;
                    }
                } else {
                    const int gt = ct >> 4, jtg = ct & 15;
                    const float* Wg; const float* bg;
                    switch (gt) {
                        case 0: Wg = Wi;  bg = bi;  break;
                        case 1: Wg = Wf;  bg = bf;  break;
                        case 2: Wg = Wie; bg = bie; break;
                        case 3: Wg = Wfe; bg = bfe; break;
                        case 4: Wg = Wz;  bg = bz;  break;
                        default: Wg = Wo; bg = bo;  break;
                    }
                    const int col = jtg * 16 + l16;
                    const float bv = bg[col];
                    bias[i] = f32x4{bv, bv, bv, bv};
                    #pragma unroll
                    for (int kk = 0; kk < 8; ++kk) {
                        short8 f;
                        #pragma unroll
                        for (int e = 0; e < 8; ++e)
                            f[e] = f2bf(Wg[(kk * 32 + lhi * 8 + e) * 256 + col]);
                        wx[i][kk] = f;
                    }
                }
            }
        }

        const size_t xb = (size_t)(g * 16 + l16) * LSEQ;
        for (int t = 0; t < LSEQ; ++t) {
            if (t >= DEPTH) {   // back-pressure: consumer g consumed slot
                int v = ld32f(&cflags[g * 32]);
                while (v < t - (DEPTH - 1)) {
                    __builtin_amdgcn_s_sleep(8);
                    v = ld32f(&cflags[g * 32]);
                }
            }
            const float* xp = x + (xb + t) * 256;
            short8 af[8];
            #pragma unroll
            for (int kk = 0; kk < 8; ++kk) {
                const f32x4 a  = *(const f32x4*)(xp + kk * 32 + lhi * 8);
                const f32x4 b2 = *(const f32x4*)(xp + kk * 32 + lhi * 8 + 4);
                short8 f;
                #pragma unroll
                for (int e = 0; e < 4; ++e) { f[e] = f2bf(a[e]); f[4 + e] = f2bf(b2[e]); }
                af[kk] = f;
            }
            f32x4 acc[4];
            #pragma unroll
            for (int i = 0; i < 4; ++i)
                if (i < nt) acc[i] = bias[i];
            #pragma unroll
            for (int kk = 0; kk < 8; ++kk) {
                #pragma unroll
                for (int i = 0; i < 4; ++i)
                    if (i < nt)
                        acc[i] = __builtin_amdgcn_mfma_f32_16x16x32_bf16(af[kk], wx[i][kk], acc[i], 0, 0, 0);
            }
            const int slot = t & (DEPTH - 1);
            #pragma unroll
            for (int i = 0; i < 4; ++i) {
                if (i < nt) {
                    const int ct = base_ct + i;
                    unsigned long long* pp =
                        (unsigned long long*)&ring[((size_t)(slot * 4 + g) * NTILE + ct) * 256 + lane * 4];
                    union { unsigned long long q[2]; f32x4 v; } u;
                    u.v = acc[i];
                    st64g(pp, u.q[0]); st64g(pp + 1, u.q[1]);
                }
            }
            asm volatile("s_waitcnt vmcnt(0)" ::: "memory");
            __syncthreads();   // all waves' ring stores complete before flag
            if (tid == 0) st32f(&pflags[p * 32], t + 1);
        }
    }
}

extern "C" void kernel_launch(void* const* d_in, const int* in_sizes, int n_in,
                              void* d_out, int out_size, void* d_ws, size_t ws_size,
                              hipStream_t stream) {
    const float* x   = (const float*)d_in[0];
    const float* td  = (const float*)d_in[1];
    const float* Wi  = (const float*)d_in[2];
    const float* bi  = (const float*)d_in[3];
    const float* Wf  = (const float*)d_in[4];
    const float* bf  = (const float*)d_in[5];
    const float* Wie = (const float*)d_in[6];
    const float* bie = (const float*)d_in[7];
    const float* Wfe = (const float*)d_in[8];
    const float* bfe = (const float*)d_in[9];
    const float* Wz  = (const float*)d_in[10];
    const float* bz  = (const float*)d_in[11];
    const float* Wo  = (const float*)d_in[12];
    const float* bo  = (const float*)d_in[13];
    const float* Wd  = (const float*)d_in[14];
    const float* bd  = (const float*)d_in[15];
    const float* be  = (const float*)d_in[16];

    int* pflags = (int*)d_ws;                                // 16 * 128 B
    int* cflags = (int*)((char*)d_ws + 2048);                // 4 * 128 B
    float* ring = (float*)((char*)d_ws + 8192);              // 4*4*97*256 f32 = 1.59 MB
    const size_t ring_end = 8192 + (size_t)DEPTH * 4 * NTILE * 256 * 4;
    const size_t percopy  = (size_t)NTILE * 4096 * 2;        // 794624 B bf16 frag copy
    unsigned short* wsW = (unsigned short*)((char*)d_ws + ring_end);
    int ncopies = 1;
    if (ws_size >= ring_end + 4 * percopy) ncopies = 4;
    else if (ws_size >= ring_end + 2 * percopy) ncopies = 2;

    hipMemsetAsync(d_ws, 0, 8192, stream);
    hipLaunchKernelGGL(ctlstm_kernel, dim3(20), dim3(512), 0, stream,
                       x, td, Wi, bi, Wf, bf, Wie, bie, Wfe, bfe, Wz, bz, Wo, bo,
                       Wd, bd, be, (float*)d_out, pflags, cflags, ring, wsW, ncopies);
}

// Round 8
// 5425.846 us; speedup vs baseline: 3.9044x; 3.9044x over previous
//
#include <hip/hip_runtime.h>
#include <hip/hip_bf16.h>

#define LSEQ  1024
#define DEPTH 4

typedef __attribute__((ext_vector_type(8))) short short8;
typedef __attribute__((ext_vector_type(4))) float f32x4;

static __device__ __forceinline__ short f2bf(float f) {
    unsigned u = __builtin_bit_cast(unsigned, f);
    u += 0x7fffu + ((u >> 16) & 1u);
    return (short)(u >> 16);
}
static __device__ __forceinline__ float sigm(float x) { return __fdividef(1.f, 1.f + __expf(-x)); }
// tanh(g/2) = 2*sigmoid(g)-1
static __device__ __forceinline__ float tanh2(float g) { return 1.f - 2.f * __fdividef(1.f, 1.f + __expf(g)); }

static __device__ __forceinline__ void st32f(int* p, int v) { __hip_atomic_store(p, v, __ATOMIC_RELAXED, __HIP_MEMORY_SCOPE_AGENT); }
static __device__ __forceinline__ int  ld32f(const int* p) { return __hip_atomic_load(p, __ATOMIC_RELAXED, __HIP_MEMORY_SCOPE_AGENT); }
static __device__ __forceinline__ void st64g(unsigned long long* p, unsigned long long v) { __hip_atomic_store(p, v, __ATOMIC_RELAXED, __HIP_MEMORY_SCOPE_AGENT); }
static __device__ __forceinline__ unsigned long long ld64g(const unsigned long long* p) { return __hip_atomic_load(p, __ATOMIC_RELAXED, __HIP_MEMORY_SCOPE_AGENT); }

// amdgpu_waves_per_eu(2,2): compiler law observed R1-R7: hipcc targets 2
// blocks/CU (512thr -> 128 VGPR) regardless of __launch_bounds__ 2nd arg,
// spilling ~80 live regs -> ~400MB/step-loop scratch on the serial path.
// Setting max waves/EU = 2 removes the occupancy incentive -> 256-VGPR budget.
extern "C" __global__ void __launch_bounds__(512)
__attribute__((amdgpu_waves_per_eu(2, 2)))
ctlstm_kernel(const float* __restrict__ x, const float* __restrict__ td,
              const float* __restrict__ Wi, const float* __restrict__ bi,
              const float* __restrict__ Wf, const float* __restrict__ bf,
              const float* __restrict__ Wie, const float* __restrict__ bie,
              const float* __restrict__ Wfe, const float* __restrict__ bfe,
              const float* __restrict__ Wz, const float* __restrict__ bz,
              const float* __restrict__ Wo, const float* __restrict__ bo,
              const float* __restrict__ Wd, const float* __restrict__ bdp,
              const float* __restrict__ betap,
              float* __restrict__ out,
              int* __restrict__ pflags, int* __restrict__ cflags,
              int* __restrict__ hflags, float* __restrict__ ring,
              unsigned short* __restrict__ hbuf)
{
    const int tid  = threadIdx.x;
    const int w    = tid >> 6;      // wave 0..7
    const int lane = tid & 63;
    const int l16  = lane & 15;
    const int lhi  = lane >> 4;

    if (blockIdx.x < 16) {
        // ===================== CONSUMER block (g, c) =====================
        const int g = blockIdx.x >> 2;
        const int c = blockIdx.x & 3;

        // [24][17][18]: mid-dim padded so tile stride = 306 dwords (== 18 mod 32)
        __shared__ float g_lds[24][17][18];                      // [T=gt*4+jt][row][col]
        __shared__ __align__(16) unsigned short h_lds[16 * 256]; // 8 KB, XOR-swizzled rows
        __shared__ float dvals[16];

        ((unsigned long long*)h_lds)[tid]       = 0ull;
        ((unsigned long long*)h_lds)[tid + 512] = 0ull;

        const float beta = betap[0];

        // ---- resident weight fragments (h-part, rows 256..511) ----
        short8 wfrag[4][8];
        #pragma unroll
        for (int i = 0; i < 4; ++i) {
            const bool hav = (i < 3) || (w == 7);
            if (hav) {
                if (i == 3) {
                    #pragma unroll
                    for (int kk = 0; kk < 8; ++kk) {
                        short8 f;
                        #pragma unroll
                        for (int e = 0; e < 8; ++e)
                            f[e] = (l16 == 0) ? f2bf(Wd[256 + kk * 32 + lhi * 8 + e]) : (short)0;
                        wfrag[i][kk] = f;
                    }
                } else {
                    const int T = w * 3 + i, gt = T >> 2, jt = T & 3;
                    const float* Wg;
                    switch (gt) {
                        case 0: Wg = Wi;  break;
                        case 1: Wg = Wf;  break;
                        case 2: Wg = Wie; break;
                        case 3: Wg = Wfe; break;
                        case 4: Wg = Wz;  break;
                        default: Wg = Wo; break;
                    }
                    const int col = c * 64 + jt * 16 + l16;
                    #pragma unroll
                    for (int kk = 0; kk < 8; ++kk) {
                        short8 f;
                        #pragma unroll
                        for (int e = 0; e < 8; ++e)
                            f[e] = f2bf(Wg[(256 + kk * 32 + lhi * 8 + e) * 256 + col]);
                        wfrag[i][kk] = f;
                    }
                }
            }
        }

        // update-phase mapping: this thread owns (row urow, cols c*64+2*up..+1)
        const int urow = tid >> 5;
        const int up   = tid & 31;
        float cC[2]  = {0.f, 0.f};
        float ceS[2] = {0.f, 0.f};
        float h2[2]  = {0.f, 0.f};

        f32x4 gx[4];
        auto load_gx = [&](int slot) {
            #pragma unroll
            for (int i = 0; i < 4; ++i) {
                const bool hav = (i < 3) || (w == 7);
                if (hav) {
                    const int T  = w * 3 + i;
                    const int ct = (i == 3) ? 96 : ((T >> 2) * 16 + c * 4 + (T & 3));
                    const unsigned long long* pp =
                        (const unsigned long long*)&ring[((size_t)(slot * 4 + g) * 97 + ct) * 256 + lane * 4];
                    union { unsigned long long q[2]; f32x4 v; } u;
                    u.q[0] = ld64g(pp); u.q[1] = ld64g(pp + 1);
                    gx[i] = u.v;
                }
            }
        };

        // prologue: producers must have finished steps 0 and 1
        {
            const int pidx = (lane & 3) * 4 + g;
            int v = (lane < 4) ? ld32f(&pflags[pidx * 32]) : 0x7fffffff;
            while (__any(v < 2)) {
                __builtin_amdgcn_s_sleep(8);
                v = (lane < 4) ? ld32f(&pflags[pidx * 32]) : 0x7fffffff;
            }
        }
        load_gx(0);
        __syncthreads();

        for (int t = 0; t < LSEQ; ++t) {
            // ---------------- phase G: recurrent GEMM + activations ----------------
            short8 hf[8];
            #pragma unroll
            for (int kk = 0; kk < 8; ++kk) {
                const int bo = l16 * 512 + ((kk * 64 + lhi * 16) ^ ((l16 & 7) << 4));
                hf[kk] = *(const short8*)((const char*)h_lds + bo);
            }
            f32x4 acc[4];
            #pragma unroll
            for (int i = 0; i < 4; ++i)
                if ((i < 3) || (w == 7)) acc[i] = gx[i];
            #pragma unroll
            for (int kk = 0; kk < 8; ++kk) {
                #pragma unroll
                for (int i = 0; i < 4; ++i)
                    if ((i < 3) || (w == 7))
                        acc[i] = __builtin_amdgcn_mfma_f32_16x16x32_bf16(hf[kk], wfrag[i][kk], acc[i], 0, 0, 0);
            }
            #pragma unroll
            for (int i = 0; i < 3; ++i) {
                const int T = w * 3 + i, gt = T >> 2;
                #pragma unroll
                for (int q = 0; q < 4; ++q) {
                    float v = acc[i][q];
                    v = (gt == 4) ? tanh2(v) : sigm(v);
                    g_lds[T][lhi * 4 + q][l16] = v;
                }
            }
            if (w == 7 && l16 == 0) {
                #pragma unroll
                for (int q = 0; q < 4; ++q) {
                    const float bg_ = beta * acc[3][q];
                    const float sp  = fmaxf(bg_, 0.f) + __logf(1.f + __expf(-fabsf(bg_)));
                    dvals[lhi * 4 + q] = __fdividef(sp, beta);
                }
            }
            __syncthreads();   // bar1: gates ready

            // ---------------- phase U: state update (own 64-col slice) ----------------
            {
                const int jtl = up >> 3;
                const int cc2 = (up & 7) * 2;
                const float2 iv  = *(const float2*)&g_lds[0 * 4 + jtl][urow][cc2];
                const float2 fv  = *(const float2*)&g_lds[1 * 4 + jtl][urow][cc2];
                const float2 iev = *(const float2*)&g_lds[2 * 4 + jtl][urow][cc2];
                const float2 fev = *(const float2*)&g_lds[3 * 4 + jtl][urow][cc2];
                const float2 zv  = *(const float2*)&g_lds[4 * 4 + jtl][urow][cc2];
                const float2 ov  = *(const float2*)&g_lds[5 * 4 + jtl][urow][cc2];
                const float dn = dvals[urow];

                // outputs[:, t, :] = h(t)
                *(float2*)(out + ((size_t)(g * 16 + urow) * LSEQ + t) * 256 + c * 64 + up * 2)
                    = make_float2(h2[0], h2[1]);

                const float cs0 = fv.x * cC[0] + iv.x * zv.x;
                const float cs1 = fv.y * cC[1] + iv.y * zv.y;
                const float ce0 = fev.x * ceS[0] + iev.x * zv.x;
                const float ce1 = fev.y * ceS[1] + iev.y * zv.y;

                if (t + 1 < LSEQ) {
                    const float dtv = td[(size_t)(g * 16 + urow) * LSEQ + (t + 1)];
                    const float e   = __expf(-dn * dtv);
                    const float cn0 = cs0 + (ce0 - cs0) * e;
                    const float cn1 = cs1 + (ce1 - cs1) * e;
                    const float hv0 = ov.x * tanh2(2.f * cn0);
                    const float hv1 = ov.y * tanh2(2.f * cn1);
                    cC[0] = cn0; cC[1] = cn1;
                    ceS[0] = ce0; ceS[1] = ce1;
                    h2[0] = hv0; h2[1] = hv1;
                    const unsigned pk = (unsigned)(unsigned short)f2bf(hv0)
                                      | ((unsigned)(unsigned short)f2bf(hv1) << 16);
                    const int par = (t + 1) & 1;
                    st32f((int*)&hbuf[((((size_t)par * 4 + g) * 4 + c) * 16 + urow) * 64 + up * 2], (int)pk);
                    const int lin = c * 128 + up * 4;
                    *(unsigned*)((char*)h_lds + urow * 512 + (lin ^ ((urow & 7) << 4))) = pk;
                } else {
                    float* so = out + (size_t)64 * LSEQ * 256 + (size_t)(g * 16 + urow) * 769;
                    const int jj = c * 64 + up * 2;
                    so[jj]           = ov.x; so[jj + 1]       = ov.y;
                    so[256 + jj]     = cs0;  so[256 + jj + 1] = cs1;
                    so[512 + jj]     = ce0;  so[512 + jj + 1] = ce1;
                    if (c == 0 && up == 0) so[768] = dn;
                }
            }
            asm volatile("s_waitcnt vmcnt(0)" ::: "memory");
            __syncthreads();   // bar2: hbuf stores globally complete

            // ---------------- phase P: publish flag, fetch remote slices, prefetch Gx ----------------
            if (t + 1 < LSEQ) {
                if (tid == 0) {
                    st32f(&hflags[(g * 4 + c) * 32], t + 1);
                    st32f(&cflags[(g * 4 + c) * 32], t + 1);
                }
                if (w >= 1 && w <= 3) {
                    const int c2 = (c + w) & 3;
                    const int* fl = &hflags[(g * 4 + c2) * 32];
                    int v = ld32f(fl);
                    while (v <= t) v = ld32f(fl);
                    const int row = lane >> 2, ch = lane & 3;
                    const unsigned long long* sp = (const unsigned long long*)
                        &hbuf[((((size_t)((t + 1) & 1) * 4 + g) * 4 + c2) * 16 + row) * 64 + ch * 16];
                    const unsigned long long q0 = ld64g(sp);
                    const unsigned long long q1 = ld64g(sp + 1);
                    const unsigned long long q2 = ld64g(sp + 2);
                    const unsigned long long q3 = ld64g(sp + 3);
                    char* hb = (char*)h_lds + row * 512;
                    const int base = c2 * 128 + ch * 32;
                    const int sw = (row & 7) << 4;
                    *(unsigned long long*)(hb + ((base)      ^ sw)) = q0;
                    *(unsigned long long*)(hb + ((base + 8)  ^ sw)) = q1;
                    *(unsigned long long*)(hb + ((base + 16) ^ sw)) = q2;
                    *(unsigned long long*)(hb + ((base + 24) ^ sw)) = q3;
                }
                load_gx((t + 1) & 3);
                // invariant: entering iter t+1, pflags >= min(t+3, LSEQ)
                const int tgt  = (t + 3 <= LSEQ) ? (t + 3) : LSEQ;
                const int pidx = (lane & 3) * 4 + g;
                int v = (lane < 4) ? ld32f(&pflags[pidx * 32]) : 0x7fffffff;
                while (__any(v < tgt)) {
                    __builtin_amdgcn_s_sleep(2);
                    v = (lane < 4) ? ld32f(&pflags[pidx * 32]) : 0x7fffffff;
                }
            }
            __syncthreads();   // bar3: h(t+1) fully in LDS
        }
    } else {
        // ===================== PRODUCER block p =====================
        const int p  = blockIdx.x - 16;   // 0..15
        const int g  = p & 3;
        const int qt = p >> 2;
        const int base_ct = qt * 24 + w * 3;
        const int nt = (qt == 3 && w == 7) ? 4 : 3;

        short8 wx[4][8];
        f32x4 bias[4];
        #pragma unroll
        for (int i = 0; i < 4; ++i) {
            if (i < nt) {
                const int ct = base_ct + i;
                if (ct == 96) {
                    const float bv = (l16 == 0) ? bdp[0] : 0.f;
                    bias[i] = f32x4{bv, bv, bv, bv};
                    #pragma unroll
                    for (int kk = 0; kk < 8; ++kk) {
                        short8 f;
                        #pragma unroll
                        for (int e = 0; e < 8; ++e)
                            f[e] = (l16 == 0) ? f2bf(Wd[kk * 32 + lhi * 8 + e]) : (short)0;
                        wx[i][kk] = f;
                    }
                } else {
                    const int gt = ct >> 4, jtg = ct & 15;
                    const float* Wg; const float* bg;
                    switch (gt) {
                        case 0: Wg = Wi;  bg = bi;  break;
                        case 1: Wg = Wf;  bg = bf;  break;
                        case 2: Wg = Wie; bg = bie; break;
                        case 3: Wg = Wfe; bg = bfe; break;
                        case 4: Wg = Wz;  bg = bz;  break;
                        default: Wg = Wo; bg = bo;  break;
                    }
                    const int col = jtg * 16 + l16;
                    const float bv = bg[col];
                    bias[i] = f32x4{bv, bv, bv, bv};
                    #pragma unroll
                    for (int kk = 0; kk < 8; ++kk) {
                        short8 f;
                        #pragma unroll
                        for (int e = 0; e < 8; ++e)
                            f[e] = f2bf(Wg[(kk * 32 + lhi * 8 + e) * 256 + col]);
                        wx[i][kk] = f;
                    }
                }
            }
        }

        const size_t xb = (size_t)(g * 16 + l16) * LSEQ;
        for (int t = 0; t < LSEQ; ++t) {
            if (t >= DEPTH) {   // back-pressure: consumers must have consumed slot
                const int cidx = g * 4 + (lane & 3);
                int v = (lane < 4) ? ld32f(&cflags[cidx * 32]) : 0x7fffffff;
                while (__any(v < t - (DEPTH - 1))) {
                    __builtin_amdgcn_s_sleep(8);
                    v = (lane < 4) ? ld32f(&cflags[cidx * 32]) : 0x7fffffff;
                }
            }
            const float* xp = x + (xb + t) * 256;
            short8 af[8];
            #pragma unroll
            for (int kk = 0; kk < 8; ++kk) {
                const f32x4 a  = *(const f32x4*)(xp + kk * 32 + lhi * 8);
                const f32x4 b2 = *(const f32x4*)(xp + kk * 32 + lhi * 8 + 4);
                short8 f;
                #pragma unroll
                for (int e = 0; e < 4; ++e) { f[e] = f2bf(a[e]); f[4 + e] = f2bf(b2[e]); }
                af[kk] = f;
            }
            f32x4 acc[4];
            #pragma unroll
            for (int i = 0; i < 4; ++i)
                if (i < nt) acc[i] = bias[i];
            #pragma unroll
            for (int kk = 0; kk < 8; ++kk) {
                #pragma unroll
                for (int i = 0; i < 4; ++i)
                    if (i < nt)
                        acc[i] = __builtin_amdgcn_mfma_f32_16x16x32_bf16(af[kk], wx[i][kk], acc[i], 0, 0, 0);
            }
            const int slot = t & (DEPTH - 1);
            #pragma unroll
            for (int i = 0; i < 4; ++i) {
                if (i < nt) {
                    const int ct = base_ct + i;
                    unsigned long long* pp =
                        (unsigned long long*)&ring[((size_t)(slot * 4 + g) * 97 + ct) * 256 + lane * 4];
                    union { unsigned long long q[2]; f32x4 v; } u;
                    u.v = acc[i];
                    st64g(pp, u.q[0]); st64g(pp + 1, u.q[1]);
                }
            }
            asm volatile("s_waitcnt vmcnt(0)" ::: "memory");
            __syncthreads();   // all waves' ring stores complete before flag
            if (tid == 0) st32f(&pflags[p * 32], t + 1);
        }
    }
}

extern "C" void kernel_launch(void* const* d_in, const int* in_sizes, int n_in,
                              void* d_out, int out_size, void* d_ws, size_t ws_size,
                              hipStream_t stream) {
    const float* x   = (const float*)d_in[0];
    const float* td  = (const float*)d_in[1];
    const float* Wi  = (const float*)d_in[2];
    const float* bi  = (const float*)d_in[3];
    const float* Wf  = (const float*)d_in[4];
    const float* bf  = (const float*)d_in[5];
    const float* Wie = (const float*)d_in[6];
    const float* bie = (const float*)d_in[7];
    const float* Wfe = (const float*)d_in[8];
    const float* bfe = (const float*)d_in[9];
    const float* Wz  = (const float*)d_in[10];
    const float* bz  = (const float*)d_in[11];
    const float* Wo  = (const float*)d_in[12];
    const float* bo  = (const float*)d_in[13];
    const float* Wd  = (const float*)d_in[14];
    const float* bd  = (const float*)d_in[15];
    const float* be  = (const float*)d_in[16];

    int* pflags = (int*)d_ws;                                // 16 * 128 B
    int* cflags = (int*)((char*)d_ws + 2048);                // 16 * 128 B
    int* hflags = (int*)((char*)d_ws + 4096);                // 16 * 128 B
    float* ring = (float*)((char*)d_ws + 8192);              // 4*4*97*256 f32 = 1.59 MB
    unsigned short* hbuf = (unsigned short*)((char*)d_ws + 8192 + 4 * 4 * 97 * 256 * 4);

    hipMemsetAsync(d_ws, 0, 8192, stream);
    hipLaunchKernelGGL(ctlstm_kernel, dim3(32), dim3(512), 0, stream,
                       x, td, Wi, bi, Wf, bf, Wie, bie, Wfe, bfe, Wz, bz, Wo, bo,
                       Wd, bd, be, (float*)d_out, pflags, cflags, hflags, ring, hbuf);
}